// Round 1
// baseline (84.766 us; speedup 1.0000x reference)
//
#include <hip/hip_runtime.h>

// QuanvolutionHybrid: 8192 x 28x28 fp32 -> 2x2 patches -> 4-qubit circuit
// (Ry encode, 2x [Ry layer + CNOT ring]) -> PauliZ feats [B,784] -> Linear(784,10)
// -> log_softmax. Fully fused, register-resident 16-amplitude simulation.
//
// R6 change vs R5: the kernel's pipes (VALU ~5us, LDS ~5us, HBM ~4us) all say
// ~6us, but the residual timed cost is ~38us -> latency/occupancy bound, not
// pipe bound. Three scheduling fixes, zero math changes:
//  1) __launch_bounds__(512, 4): cap VGPRs at 128 so 16 waves/CU are resident
//     (previously no min-waves arg -> allocator free to blow past 128 -> 8/CU).
//  2) software-pipeline the x loads: prefetch patch k+1's two float2 while
//     computing patch k (branchless clamped address on the tail iteration).
//  3) 16 rows/block (512 thr): halves per-row W-staging cost; grid = 512 blocks
//     = exactly 2 blocks/CU, one occupancy batch, staging overlaps compute.
// Carried: W in LDS (31.4KB, broadcast-free reads); layer-0 Ry folded into
// encoding sincos; layer-1 in tangent form, (prod cos)^2 deferred to one fmaf
// per row. wire w <-> bit (3-w).

template <int BIT>
static __device__ __forceinline__ void apply_ry_tan(float (&a)[16], float t) {
#pragma unroll
    for (int i = 0; i < 16; ++i) {
        if (i & (1 << BIT)) continue;
        float a0 = a[i];
        float a1 = a[i | (1 << BIT)];
        a[i]              = fmaf(-t, a1, a0);   // a0 - t*a1
        a[i | (1 << BIT)] = fmaf( t, a0, a1);   // a1 + t*a0
    }
}

template <int CBIT, int TBIT>
static __device__ __forceinline__ void apply_cnot(float (&a)[16]) {
#pragma unroll
    for (int i = 0; i < 16; ++i) {
        if ((i & (1 << CBIT)) && !(i & (1 << TBIT))) {
            float t = a[i];
            a[i] = a[i | (1 << TBIT)];
            a[i | (1 << TBIT)] = t;
        }
    }
}

__global__ __launch_bounds__(512, 4) void quanv_fused_kernel(
    const float* __restrict__ x,       // [B,28,28]
    const float* __restrict__ params,  // [2,4]
    const float* __restrict__ W,       // [10,784]
    const float* __restrict__ bias,    // [10]
    float* __restrict__ out,           // [B,10]
    int B)
{
    __shared__ float Wl[10 * 784];     // 31360 B; 2 blocks/CU -> 62.7 KB, fits

    // Cooperative W staging: 1960 float4s over 512 threads (4 rounds, coalesced).
    {
        const float4* Wg4 = (const float4*)W;
        float4* Wl4 = (float4*)Wl;
        for (int t = threadIdx.x; t < 1960; t += 512) Wl4[t] = Wg4[t];
    }
    __syncthreads();   // before any row guard: all threads must reach this

    const int lane = threadIdx.x & 63;
    const int lid  = lane & 31;                 // lane within 32-lane row group
    const int wave = threadIdx.x >> 6;          // 0..7
    const int row  = blockIdx.x * 16 + wave * 2 + (lane >> 5);
    if (row >= B) return;

    // Layer-0 half-angles (folded into encoding); layer-1 tangents + deferred scale.
    float h0[4], t1w[4];
    float scale2 = 1.0f;
#pragma unroll
    for (int w = 0; w < 4; ++w) {
        h0[w] = 0.5f * params[w];
        float s, c;
        __sincosf(0.5f * params[4 + w], &s, &c);
        t1w[w] = s / c;          // tan(theta/2); params fixed, |c| not tiny in practice
        scale2 *= c;
    }
    scale2 *= scale2;            // (prod_w cos)^2 — applied once per row at the end

    float logit[10];
#pragma unroll
    for (int c = 0; c < 10; ++c) logit[c] = 0.0f;

    const float* xrow = x + (size_t)row * 784;

    // Software-pipelined patch loop. Patch p=(i,j): wire0=(2i,2j) wire1=(2i,2j+1)
    // wire2=(2i+1,2j) wire3=(2i+1,2j+1). Prefetch p+32 while computing p.
    int i = lid / 14;
    int j = lid - i * 14;
    int ai = i * 56 + j * 2;                    // float offset of patch base (8B-aligned)
    float2 c0 = *(const float2*)(xrow + ai);
    float2 c1 = *(const float2*)(xrow + ai + 28);

#pragma unroll 1
    for (int p = lid; p < 196; p += 32) {
        // Advance (i,j) by 32 patches (= 2 rows + 4 cols) with single carry,
        // then issue next iteration's loads (clamped to current addr on tail).
        j += 4; i += 2;
        if (j >= 14) { j -= 14; ++i; }
        const int an = (i < 14) ? (i * 56 + j * 2) : ai;
        const float2 n0 = *(const float2*)(xrow + an);
        const float2 n1 = *(const float2*)(xrow + an + 28);

        // Encoding Ry(x) fused with layer-0 Ry(p0): half-angle = x/2 + p0/2.
        float e0, s0, e1, s1, e2, s2, e3, s3;
        __sincosf(fmaf(0.5f, c0.x, h0[0]), &s0, &e0);
        __sincosf(fmaf(0.5f, c0.y, h0[1]), &s1, &e1);
        __sincosf(fmaf(0.5f, c1.x, h0[2]), &s2, &e2);
        __sincosf(fmaf(0.5f, c1.y, h0[3]), &s3, &e3);

        // Product state: amp[idx] = p01[idx>>2] * p23[idx&3]  (24 mul)
        float p01[4] = {e0 * e1, e0 * s1, s0 * e1, s0 * s1};
        float p23[4] = {e2 * e3, e2 * s3, s2 * e3, s2 * s3};
        float amp[16];
#pragma unroll
        for (int idx = 0; idx < 16; ++idx)
            amp[idx] = p01[idx >> 2] * p23[idx & 3];

        // Layer-0 CNOT ring (register renames, free).
        apply_cnot<3, 2>(amp);
        apply_cnot<2, 1>(amp);
        apply_cnot<1, 0>(amp);
        apply_cnot<0, 3>(amp);
        // Layer-1 Ry, tangent form (scale deferred): 2 FMA per pair.
        apply_ry_tan<3>(amp, t1w[0]);
        apply_ry_tan<2>(amp, t1w[1]);
        apply_ry_tan<1>(amp, t1w[2]);
        apply_ry_tan<0>(amp, t1w[3]);
        // Layer-1 CNOT ring (renames).
        apply_cnot<3, 2>(amp);
        apply_cnot<2, 1>(amp);
        apply_cnot<1, 0>(amp);
        apply_cnot<0, 3>(amp);

        // PauliZ expvals (unnormalized by scale2) via shared sum tree.
        float pr[16];
#pragma unroll
        for (int idx = 0; idx < 16; ++idx) pr[idx] = amp[idx] * amp[idx];

        float sp[8], dp[8];
#pragma unroll
        for (int k = 0; k < 8; ++k) {
            sp[k] = pr[2 * k] + pr[2 * k + 1];
            dp[k] = pr[2 * k] - pr[2 * k + 1];
        }
        float z3 = ((dp[0] + dp[1]) + (dp[2] + dp[3])) + ((dp[4] + dp[5]) + (dp[6] + dp[7]));
        float t[4], u[4];
#pragma unroll
        for (int k = 0; k < 4; ++k) {
            t[k] = sp[2 * k] + sp[2 * k + 1];
            u[k] = sp[2 * k] - sp[2 * k + 1];
        }
        float z2 = (u[0] + u[1]) + (u[2] + u[3]);
        float z1 = (t[0] - t[1]) + (t[2] - t[3]);
        float z0 = (t[0] + t[1]) - (t[2] + t[3]);

        // Logit accumulation from LDS: lanes stride 16B (contiguous 512B per group,
        // both 32-lane groups read the SAME addresses -> broadcast, conflict-free).
        const float* wp = Wl + 4 * p;
#pragma unroll
        for (int c = 0; c < 10; ++c) {
            float4 wv = *(const float4*)(wp + c * 784);
            logit[c] = fmaf(z0, wv.x, fmaf(z1, wv.y, fmaf(z2, wv.z, fmaf(z3, wv.w, logit[c]))));
        }

        // Rotate the software pipeline.
        c0 = n0; c1 = n1; ai = an;
    }

    // Butterfly reduction within each 32-lane row group.
#pragma unroll
    for (int off = 16; off > 0; off >>= 1) {
#pragma unroll
        for (int c = 0; c < 10; ++c)
            logit[c] += __shfl_xor(logit[c], off, 64);
    }

    if (lid == 0) {   // lanes 0 and 32 hold their row's full logits
        float v[10];
        float m = -1e30f;
#pragma unroll
        for (int c = 0; c < 10; ++c) {
            v[c] = fmaf(scale2, logit[c], bias[c]);   // deferred tangent-form scale
            m = fmaxf(m, v[c]);
        }
        float sum = 0.f;
#pragma unroll
        for (int c = 0; c < 10; ++c) sum += __expf(v[c] - m);
        float lse = m + __logf(sum);

        float2* o = (float2*)(out + (size_t)row * 10);   // 40B rows -> 8B aligned
#pragma unroll
        for (int k = 0; k < 5; ++k)
            o[k] = make_float2(v[2 * k] - lse, v[2 * k + 1] - lse);
    }
}

extern "C" void kernel_launch(void* const* d_in, const int* in_sizes, int n_in,
                              void* d_out, int out_size, void* d_ws, size_t ws_size,
                              hipStream_t stream) {
    const float* x      = (const float*)d_in[0];
    const float* params = (const float*)d_in[1];
    const float* W      = (const float*)d_in[2];
    const float* bias   = (const float*)d_in[3];
    float* out          = (float*)d_out;

    const int B = in_sizes[0] / 784;          // 8192
    const int blocks = (B + 15) / 16;         // 16 rows per block (2 per wave)

    hipLaunchKernelGGL(quanv_fused_kernel, dim3(blocks), dim3(512), 0, stream,
                       x, params, W, bias, out, B);
}

// Round 2
// 79.360 us; speedup vs baseline: 1.0681x; 1.0681x over previous
//
#include <hip/hip_runtime.h>

// QuanvolutionHybrid: 8192 x 28x28 fp32 -> 2x2 patches -> 4-qubit circuit
// (Ry encode, 2x [Ry layer + CNOT ring]) -> PauliZ feats [B,784] -> Linear(784,10)
// -> log_softmax. Fully fused.
//
// R7 change vs R6: replace the register-resident 16-amplitude simulation with a
// CLOSED-FORM Heisenberg evaluation of the four PauliZ expectations. Conjugating
// Z_w through CNOT-ring, Ry-layer, CNOT-ring gives Pauli strings; every string
// containing Y has zero expectation under the real product encoding state, so
// only 18 terms survive (z0:4, z1:2, z2:4, z3:8):
//   z_w = sum_t kappa_t(params) * M_t(cos a_b, sin a_b),  a_b = x_b + theta0_b
// kappa_t are per-launch constants (computed once per thread); M_t are monomials
// built from 4 sincos + 23 muls. Per-patch VALU ~200 -> ~105. Also removes the
// tan(theta/2) form and the deferred (prod cos)^2 scale entirely (exact algebra).
// Bit convention unchanged: wire w <-> bit (3-w). Verified two ways (Pauli letter
// algebra + symplectic x/z-mask with sign tracking) and by limit cases.
// Carried from R5/R6: W staged in LDS (31.4KB, broadcast conflict-free reads),
// 512 thr / 16 rows per block, software-pipelined x loads, launch_bounds(512,4).

__global__ __launch_bounds__(512, 4) void quanv_fused_kernel(
    const float* __restrict__ x,       // [B,28,28]
    const float* __restrict__ params,  // [2,4]
    const float* __restrict__ W,       // [10,784]
    const float* __restrict__ bias,    // [10]
    float* __restrict__ out,           // [B,10]
    int B)
{
    __shared__ float Wl[10 * 784];     // 31360 B; 2 blocks/CU -> 62.7 KB, fits

    // Cooperative W staging: 1960 float4s over 512 threads (4 rounds, coalesced).
    {
        const float4* Wg4 = (const float4*)W;
        float4* Wl4 = (float4*)Wl;
        for (int t = threadIdx.x; t < 1960; t += 512) Wl4[t] = Wg4[t];
    }
    __syncthreads();   // before any row guard: all threads must reach this

    const int lane = threadIdx.x & 63;
    const int lid  = lane & 31;                 // lane within 32-lane row group
    const int wave = threadIdx.x >> 6;          // 0..7
    const int row  = blockIdx.x * 16 + wave * 2 + (lane >> 5);
    if (row >= B) return;

    // ---- Per-thread constants from params (cheap, once per row) ----
    // Layer-0 FULL angles, wire-indexed (folded into encoding angle a = x + t0).
    const float t0w0 = params[0], t0w1 = params[1], t0w2 = params[2], t0w3 = params[3];
    // Layer-1 cos/sin of FULL angles, bit-indexed: bit b <- wire (3-b).
    float cB[4], sB[4];
#pragma unroll
    for (int w = 0; w < 4; ++w) __sincosf(params[4 + w], &sB[3 - w], &cB[3 - w]);

    // Surviving Heisenberg terms; minus signs folded into the kappa constants.
    // z0 (wire0 = Z_bit3 -> pre-ring Z-string on bits {0,1,2}):
    const float k0a =  cB[0] * cB[1] * cB[2];   // * C0C2C3
    const float k0b = -cB[0] * cB[1] * sB[2];   // * C0S1S2
    const float k0c = -sB[0] * cB[1] * cB[2];   // * S0C1S2S3
    const float k0d = -sB[0] * sB[1] * sB[2];   // * S3
    // z1 (wire1 = Z_bit2 -> bits {2,3}):
    const float k1a =  cB[2] * cB[3];           // * C0C1C3
    const float k1b =  sB[2] * sB[3];           // * S1S3
    // z2 (wire2 = Z_bit1 -> bits {1,2,3}):
    const float k2a =  cB[1] * cB[2] * cB[3];   // * C0C2
    const float k2b = -cB[1] * cB[2] * sB[3];   // * C1S2S3
    const float k2c = -cB[1] * sB[2] * cB[3];   // * C0S1S2C3
    const float k2d = -sB[1] * sB[2] * sB[3];   // * S0S3
    // z3 (wire3 = Z_bit0 -> bits {0,1,2,3}):
    const float k3a =  cB[0] * cB[1] * cB[2] * cB[3];   // * C1C3
    const float k3b =  cB[0] * cB[1] * sB[2] * sB[3];   // * C0S1S3
    const float k3c = -cB[0] * sB[1] * cB[2] * cB[3];   // * S0S1C2
    const float k3d =  cB[0] * sB[1] * sB[2] * cB[3];   // * S0S2C3
    const float k3e =  sB[0] * cB[1] * cB[2] * sB[3];   // * S0C1
    const float k3f = -sB[0] * sB[1] * cB[2] * sB[3];   // * S1C2C3
    const float k3g = -sB[0] * sB[1] * sB[2] * cB[3];   // * C0C1C2S3
    const float k3h =  sB[0] * sB[1] * sB[2] * sB[3];   // * S2

    float logit[10];
#pragma unroll
    for (int c = 0; c < 10; ++c) logit[c] = 0.0f;

    const float* xrow = x + (size_t)row * 784;

    // Software-pipelined patch loop. Patch p=(i,j): wire0=(2i,2j) wire1=(2i,2j+1)
    // wire2=(2i+1,2j) wire3=(2i+1,2j+1). Prefetch p+32 while computing p.
    int i = lid / 14;
    int j = lid - i * 14;
    int ai = i * 56 + j * 2;                    // float offset of patch base (8B-aligned)
    float2 v0 = *(const float2*)(xrow + ai);
    float2 v1 = *(const float2*)(xrow + ai + 28);

#pragma unroll 1
    for (int p = lid; p < 196; p += 32) {
        // Advance (i,j) by 32 patches (= 2 rows + 4 cols) with single carry,
        // then issue next iteration's loads (clamped to current addr on tail).
        j += 4; i += 2;
        if (j >= 14) { j -= 14; ++i; }
        const int an = (i < 14) ? (i * 56 + j * 2) : ai;
        const float2 n0 = *(const float2*)(xrow + an);
        const float2 n1 = *(const float2*)(xrow + an + 28);

        // Full encoding angles (layer-0 folded): bit3<-wire0, bit2<-wire1,
        // bit1<-wire2, bit0<-wire3.  C_b = cos a_b, S_b = sin a_b.
        float C0, S0, C1, S1, C2, S2, C3, S3;
        __sincosf(v0.x + t0w0, &S3, &C3);
        __sincosf(v0.y + t0w1, &S2, &C2);
        __sincosf(v1.x + t0w2, &S1, &C1);
        __sincosf(v1.y + t0w3, &S0, &C0);

        // 23 monomial muls (shared subproducts).
        const float C0C2 = C0 * C2, C0C1 = C0 * C1, C1C3 = C1 * C3, C2C3 = C2 * C3;
        const float S1S2 = S1 * S2, S2S3 = S2 * S3, S1S3 = S1 * S3;
        const float S0S1 = S0 * S1, S0S2 = S0 * S2, S0S3 = S0 * S3;
        const float S0C1 = S0 * C1;
        const float C0C2C3   = C0C2 * C3;
        const float C0S1S2   = C0 * S1S2;
        const float C0S1S2C3 = C0S1S2 * C3;
        const float S0C1S2S3 = S0C1 * S2S3;
        const float C0C1C3   = C0C1 * C3;
        const float C1S2S3   = C1 * S2S3;
        const float C0S1S3   = C0 * S1S3;
        const float S0S1C2   = S0S1 * C2;
        const float S0S2C3   = S0S2 * C3;
        const float S1C2C3   = S1 * C2C3;
        const float C0C1C2S3 = (C0C1 * C2) * S3;

        // PauliZ expectations, exact (18 terms).
        const float z0 = fmaf(k0a, C0C2C3,
                         fmaf(k0b, C0S1S2,
                         fmaf(k0c, S0C1S2S3, k0d * S3)));
        const float z1 = fmaf(k1a, C0C1C3, k1b * S1S3);
        const float z2 = fmaf(k2a, C0C2,
                         fmaf(k2b, C1S2S3,
                         fmaf(k2c, C0S1S2C3, k2d * S0S3)));
        const float z3 = fmaf(k3a, C1C3,
                         fmaf(k3b, C0S1S3,
                         fmaf(k3c, S0S1C2,
                         fmaf(k3d, S0S2C3,
                         fmaf(k3e, S0C1,
                         fmaf(k3f, S1C2C3,
                         fmaf(k3g, C0C1C2S3, k3h * S2)))))));

        // Logit accumulation from LDS: lanes stride 16B (contiguous 512B per group,
        // both 32-lane groups read the SAME addresses -> broadcast, conflict-free).
        const float* wp = Wl + 4 * p;
#pragma unroll
        for (int c = 0; c < 10; ++c) {
            float4 wv = *(const float4*)(wp + c * 784);
            logit[c] = fmaf(z0, wv.x, fmaf(z1, wv.y, fmaf(z2, wv.z, fmaf(z3, wv.w, logit[c]))));
        }

        // Rotate the software pipeline.
        v0 = n0; v1 = n1; ai = an;
    }

    // Butterfly reduction within each 32-lane row group.
#pragma unroll
    for (int off = 16; off > 0; off >>= 1) {
#pragma unroll
        for (int c = 0; c < 10; ++c)
            logit[c] += __shfl_xor(logit[c], off, 64);
    }

    if (lid == 0) {   // lanes 0 and 32 hold their row's full logits
        float v[10];
        float m = -1e30f;
#pragma unroll
        for (int c = 0; c < 10; ++c) {
            v[c] = logit[c] + bias[c];
            m = fmaxf(m, v[c]);
        }
        float sum = 0.f;
#pragma unroll
        for (int c = 0; c < 10; ++c) sum += __expf(v[c] - m);
        float lse = m + __logf(sum);

        float2* o = (float2*)(out + (size_t)row * 10);   // 40B rows -> 8B aligned
#pragma unroll
        for (int k = 0; k < 5; ++k)
            o[k] = make_float2(v[2 * k] - lse, v[2 * k + 1] - lse);
    }
}

extern "C" void kernel_launch(void* const* d_in, const int* in_sizes, int n_in,
                              void* d_out, int out_size, void* d_ws, size_t ws_size,
                              hipStream_t stream) {
    const float* x      = (const float*)d_in[0];
    const float* params = (const float*)d_in[1];
    const float* W      = (const float*)d_in[2];
    const float* bias   = (const float*)d_in[3];
    float* out          = (float*)d_out;

    const int B = in_sizes[0] / 784;          // 8192
    const int blocks = (B + 15) / 16;         // 16 rows per block (2 per wave)

    hipLaunchKernelGGL(quanv_fused_kernel, dim3(blocks), dim3(512), 0, stream,
                       x, params, W, bias, out, B);
}

// Round 3
// 78.922 us; speedup vs baseline: 1.0740x; 1.0056x over previous
//
#include <hip/hip_runtime.h>

// QuanvolutionHybrid: 8192 x 28x28 fp32 -> 2x2 patches -> 4-qubit circuit
// (Ry encode, 2x [Ry layer + CNOT ring]) -> PauliZ feats [B,784] -> Linear(784,10)
// -> log_softmax. Fully fused.
//
// R8 change vs R7: amortize the dominant LDS pipe. Kernel-side pipe arithmetic:
// VALU ~2.5us but W-fragment reads = 16 waves/CU x 70 ds_read_b128 x ~12cyc
// ~= 5.6us -> the kernel is LDS-read bound. Each thread now owns TWO rows, so
// every W float4 read feeds 8 FMAs instead of 4: W-read wave-ops per CU halve
// (1120 -> 560), total VALU unchanged (same work in half the waves, 2/SIMD).
// Geometry: 512-thread blocks, each 32-lane group owns rows {g*2, g*2+1};
// 32 rows/block -> grid = 256 = exactly 1 block/CU.
// Carried from R7 (verbatim math): closed-form Heisenberg evaluation of the four
// PauliZ expvals — 18 surviving Pauli-string terms (z0:4, z1:2, z2:4, z3:8),
//   z_w = sum_t kappa_t(params) * M_t(cos a_b, sin a_b),  a_b = x_b + theta0_b,
// 4 sincos + 23 monomial muls + 18 FMA per patch per row. wire w <-> bit (3-w).
// Carried from R5/R6: W staged in LDS (31.4KB, broadcast conflict-free reads),
// software-pipelined x loads.

__global__ __launch_bounds__(512, 2) void quanv_fused_kernel(
    const float* __restrict__ x,       // [B,28,28]
    const float* __restrict__ params,  // [2,4]
    const float* __restrict__ W,       // [10,784]
    const float* __restrict__ bias,    // [10]
    float* __restrict__ out,           // [B,10]
    int B)
{
    __shared__ float Wl[10 * 784];     // 31360 B; 1 block/CU

    // Cooperative W staging: 1960 float4s over 512 threads (4 rounds, coalesced).
    {
        const float4* Wg4 = (const float4*)W;
        float4* Wl4 = (float4*)Wl;
        for (int t = threadIdx.x; t < 1960; t += 512) Wl4[t] = Wg4[t];
    }
    __syncthreads();   // before any row guard: all threads must reach this

    const int lid  = threadIdx.x & 31;          // lane within 32-lane row group
    const int grp  = threadIdx.x >> 5;          // 0..15
    const int row0 = blockIdx.x * 32 + grp * 2;
    if (row0 >= B) return;
    const bool has1 = (row0 + 1) < B;
    const float* xr0 = x + (size_t)row0 * 784;
    const float* xr1 = x + (size_t)(has1 ? row0 + 1 : row0) * 784;

    // ---- Per-thread constants from params (cheap, once) ----
    // Layer-0 FULL angles, wire-indexed (folded into encoding angle a = x + t0).
    const float t0w0 = params[0], t0w1 = params[1], t0w2 = params[2], t0w3 = params[3];
    // Layer-1 cos/sin of FULL angles, bit-indexed: bit b <- wire (3-b).
    float cB[4], sB[4];
#pragma unroll
    for (int w = 0; w < 4; ++w) __sincosf(params[4 + w], &sB[3 - w], &cB[3 - w]);

    // Surviving Heisenberg terms; minus signs folded into the kappa constants.
    const float k0a =  cB[0] * cB[1] * cB[2];   // * C0C2C3
    const float k0b = -cB[0] * cB[1] * sB[2];   // * C0S1S2
    const float k0c = -sB[0] * cB[1] * cB[2];   // * S0C1S2S3
    const float k0d = -sB[0] * sB[1] * sB[2];   // * S3
    const float k1a =  cB[2] * cB[3];           // * C0C1C3
    const float k1b =  sB[2] * sB[3];           // * S1S3
    const float k2a =  cB[1] * cB[2] * cB[3];   // * C0C2
    const float k2b = -cB[1] * cB[2] * sB[3];   // * C1S2S3
    const float k2c = -cB[1] * sB[2] * cB[3];   // * C0S1S2C3
    const float k2d = -sB[1] * sB[2] * sB[3];   // * S0S3
    const float k3a =  cB[0] * cB[1] * cB[2] * cB[3];   // * C1C3
    const float k3b =  cB[0] * cB[1] * sB[2] * sB[3];   // * C0S1S3
    const float k3c = -cB[0] * sB[1] * cB[2] * cB[3];   // * S0S1C2
    const float k3d =  cB[0] * sB[1] * sB[2] * cB[3];   // * S0S2C3
    const float k3e =  sB[0] * cB[1] * cB[2] * sB[3];   // * S0C1
    const float k3f = -sB[0] * sB[1] * cB[2] * sB[3];   // * S1C2C3
    const float k3g = -sB[0] * sB[1] * sB[2] * cB[3];   // * C0C1C2S3
    const float k3h =  sB[0] * sB[1] * sB[2] * sB[3];   // * S2

    // Closed-form z for one patch of one row (R7 math, verbatim).
    auto eval_z = [&](float2 u0, float2 u1, float* z) {
        float C0, S0, C1, S1, C2, S2, C3, S3;
        __sincosf(u0.x + t0w0, &S3, &C3);
        __sincosf(u0.y + t0w1, &S2, &C2);
        __sincosf(u1.x + t0w2, &S1, &C1);
        __sincosf(u1.y + t0w3, &S0, &C0);

        const float C0C2 = C0 * C2, C0C1 = C0 * C1, C1C3 = C1 * C3, C2C3 = C2 * C3;
        const float S1S2 = S1 * S2, S2S3 = S2 * S3, S1S3 = S1 * S3;
        const float S0S1 = S0 * S1, S0S2 = S0 * S2, S0S3 = S0 * S3;
        const float S0C1 = S0 * C1;
        const float C0C2C3   = C0C2 * C3;
        const float C0S1S2   = C0 * S1S2;
        const float C0S1S2C3 = C0S1S2 * C3;
        const float S0C1S2S3 = S0C1 * S2S3;
        const float C0C1C3   = C0C1 * C3;
        const float C1S2S3   = C1 * S2S3;
        const float C0S1S3   = C0 * S1S3;
        const float S0S1C2   = S0S1 * C2;
        const float S0S2C3   = S0S2 * C3;
        const float S1C2C3   = S1 * C2C3;
        const float C0C1C2S3 = (C0C1 * C2) * S3;

        z[0] = fmaf(k0a, C0C2C3,
               fmaf(k0b, C0S1S2,
               fmaf(k0c, S0C1S2S3, k0d * S3)));
        z[1] = fmaf(k1a, C0C1C3, k1b * S1S3);
        z[2] = fmaf(k2a, C0C2,
               fmaf(k2b, C1S2S3,
               fmaf(k2c, C0S1S2C3, k2d * S0S3)));
        z[3] = fmaf(k3a, C1C3,
               fmaf(k3b, C0S1S3,
               fmaf(k3c, S0S1C2,
               fmaf(k3d, S0S2C3,
               fmaf(k3e, S0C1,
               fmaf(k3f, S1C2C3,
               fmaf(k3g, C0C1C2S3, k3h * S2)))))));
    };

    float lg[2][10];
#pragma unroll
    for (int c = 0; c < 10; ++c) { lg[0][c] = 0.0f; lg[1][c] = 0.0f; }

    // Software-pipelined patch loop. Patch p=(i,j): wire0=(2i,2j) wire1=(2i,2j+1)
    // wire2=(2i+1,2j) wire3=(2i+1,2j+1). Prefetch p+32 (both rows) while computing p.
    int i = lid / 14;
    int j = lid - i * 14;
    int ai = i * 56 + j * 2;                    // float offset of patch base (8B-aligned)
    float2 a00 = *(const float2*)(xr0 + ai), a01 = *(const float2*)(xr0 + ai + 28);
    float2 a10 = *(const float2*)(xr1 + ai), a11 = *(const float2*)(xr1 + ai + 28);

#pragma unroll 1
    for (int p = lid; p < 196; p += 32) {
        // Advance (i,j) by 32 patches (= 2 rows + 4 cols) with single carry,
        // then issue next iteration's loads (clamped to current addr on tail).
        j += 4; i += 2;
        if (j >= 14) { j -= 14; ++i; }
        const int an = (i < 14) ? (i * 56 + j * 2) : ai;
        const float2 b00 = *(const float2*)(xr0 + an), b01 = *(const float2*)(xr0 + an + 28);
        const float2 b10 = *(const float2*)(xr1 + an), b11 = *(const float2*)(xr1 + an + 28);

        float z[2][4];
        eval_z(a00, a01, z[0]);
        eval_z(a10, a11, z[1]);

        // Logit accumulation from LDS: one W float4 feeds BOTH rows (8 FMA/read).
        // Lanes stride 16B (contiguous 512B per group); all groups read the same
        // address sequence -> broadcast, conflict-free.
        const float* wp = Wl + 4 * p;
#pragma unroll
        for (int c = 0; c < 10; ++c) {
            float4 wv = *(const float4*)(wp + c * 784);
            lg[0][c] = fmaf(z[0][0], wv.x, fmaf(z[0][1], wv.y,
                       fmaf(z[0][2], wv.z, fmaf(z[0][3], wv.w, lg[0][c]))));
            lg[1][c] = fmaf(z[1][0], wv.x, fmaf(z[1][1], wv.y,
                       fmaf(z[1][2], wv.z, fmaf(z[1][3], wv.w, lg[1][c]))));
        }

        // Rotate the software pipeline.
        a00 = b00; a01 = b01; a10 = b10; a11 = b11; ai = an;
    }

    // Butterfly reduction within each 32-lane row group (offsets <32 stay in-half).
#pragma unroll
    for (int off = 16; off > 0; off >>= 1) {
#pragma unroll
        for (int c = 0; c < 10; ++c) {
            lg[0][c] += __shfl_xor(lg[0][c], off, 64);
            lg[1][c] += __shfl_xor(lg[1][c], off, 64);
        }
    }

    if (lid == 0) {   // lane 0 of each 32-group holds both rows' full logits
#pragma unroll
        for (int r = 0; r < 2; ++r) {
            if (r == 1 && !has1) break;
            float v[10];
            float m = -1e30f;
#pragma unroll
            for (int c = 0; c < 10; ++c) {
                v[c] = lg[r][c] + bias[c];
                m = fmaxf(m, v[c]);
            }
            float sum = 0.f;
#pragma unroll
            for (int c = 0; c < 10; ++c) sum += __expf(v[c] - m);
            float lse = m + __logf(sum);

            float2* o = (float2*)(out + (size_t)(row0 + r) * 10);  // 40B rows, 8B aligned
#pragma unroll
            for (int k = 0; k < 5; ++k)
                o[k] = make_float2(v[2 * k] - lse, v[2 * k + 1] - lse);
        }
    }
}

extern "C" void kernel_launch(void* const* d_in, const int* in_sizes, int n_in,
                              void* d_out, int out_size, void* d_ws, size_t ws_size,
                              hipStream_t stream) {
    const float* x      = (const float*)d_in[0];
    const float* params = (const float*)d_in[1];
    const float* W      = (const float*)d_in[2];
    const float* bias   = (const float*)d_in[3];
    float* out          = (float*)d_out;

    const int B = in_sizes[0] / 784;          // 8192
    const int blocks = (B + 31) / 32;         // 32 rows per block (2 per 32-lane group)

    hipLaunchKernelGGL(quanv_fused_kernel, dim3(blocks), dim3(512), 0, stream,
                       x, params, W, bias, out, B);
}